// Round 4
// baseline (197.001 us; speedup 1.0000x reference)
//
#include <hip/hip_runtime.h>
#include <math.h>

#define SDF_W      7000.0f
#define EIK_W      600.0f
#define ORI_W      500.0f
#define NEAR_ORI_W 10.0f
#define GRADN_W    200.0f

#define TILE   4096          // points per LDS tile (64 KB of float4)
#define NWAVE  8             // 512-thread blocks
#define QPL    8             // queries per lane -> 512 queries per block
#define CHK    64            // chunk granularity for index recovery (= wave size)
#define WS_STRIDE 512        // per-array stride (floats) for block partials
#define WS_REC 4096          // float offset of per-query records

typedef float v2f __attribute__((ext_vector_type(2)));

// ws float layout:
//   [k*512 .. k*512+RB) : recover-block partials, k = 0:ori 1:nori 2:sdf 3:eik 4:gn
//   [4096 ...)          : records, float4 per (query, split): {M1, M2, c1, c2}

__device__ __forceinline__ float nh2(float sx, float sy, float sz) {
    return -0.5f * fmaf(sx, sx, fmaf(sy, sy, sz * sz));
}
// Deterministic score; bit-identical chain in nn_scan and recover_k.
__device__ __forceinline__ float score(float qx, float qy, float qz,
                                       float sx, float sy, float sz, float nh) {
    return fmaf(qx, sx, fmaf(qy, sy, fmaf(qz, sz, nh)));
}

// ---------------------------------------------------------------------------
// Hot kernel: top-2 score values per (query, S-split) + chunk ids.
// 8 queries/lane (512/block); 8 waves split the tile; `splits` blocks split S.
// Inner update: M2 = med3(g, M1, M2); M1 = max(M1, g)  (2 ops, no indices).
// Score for a query PAIR via packed fp32 fma (v_pk_fma_f32 on gfx950).
// ---------------------------------------------------------------------------
__global__ __launch_bounds__(512) void nn_scan(
    const float* __restrict__ offq, const float* __restrict__ nearq,
    const float* __restrict__ surf,
    float* __restrict__ ws, int S, int Qoff, int QT, int splits, int segLen)
{
    __shared__ float4 tile[TILE];                 // 64 KB; reused for merge recs
    const int t    = threadIdx.x;
    const int lane = t & 63;
    const int wv   = __builtin_amdgcn_readfirstlane(t >> 6);   // 0..7

    const int qg = blockIdx.x / splits;
    const int sp = blockIdx.x % splits;
    const int sb = sp * segLen;
    int se = sb + segLen; if (se > S) se = S;

    // ---- load 8 queries per lane ----
    float qx[QPL], qy[QPL], qz[QPL];
    #pragma unroll
    for (int k = 0; k < QPL; ++k) {
        int q = qg * 512 + k * 64 + lane;
        float x = 0.f, y = 0.f, z = 0.f;
        if (q < QT) {
            const float* p = (q < Qoff) ? (offq + 3 * q) : (nearq + 3 * (q - Qoff));
            x = p[0]; y = p[1]; z = p[2];
        }
        qx[k] = x; qy[k] = y; qz[k] = z;
    }
    v2f qx2[QPL/2], qy2[QPL/2], qz2[QPL/2];
    #pragma unroll
    for (int p = 0; p < QPL/2; ++p) {
        qx2[p] = (v2f){qx[2*p], qx[2*p+1]};
        qy2[p] = (v2f){qy[2*p], qy[2*p+1]};
        qz2[p] = (v2f){qz[2*p], qz[2*p+1]};
    }

    float M1[QPL], M2[QPL], P1[QPL], P2[QPL];
    int   c1[QPL], c2[QPL];
    const int cinit = (sb < S ? sb : 0) >> 6;
    #pragma unroll
    for (int k = 0; k < QPL; ++k) {
        M1[k] = -3.0e38f; M2[k] = -3.0e38f;
        P1[k] = -3.0e38f; P2[k] = -3.0e38f;
        c1[k] = cinit;    c2[k] = cinit;
    }

    for (int base = sb; base < se; base += TILE) {
        __syncthreads();
        // ---- stage up to 4096 points (8/thread) as (x,y,z,-|s|^2/2) ----
        {
            int p0 = base + t * 8;
            float4* dst = tile + t * 8;
            if (p0 + 8 <= se) {
                const float4* g4 = (const float4*)(surf + 3 * (size_t)p0);
                float4 a = g4[0], b = g4[1], c = g4[2], d = g4[3], e = g4[4], f = g4[5];
                dst[0] = make_float4(a.x, a.y, a.z, nh2(a.x, a.y, a.z));
                dst[1] = make_float4(a.w, b.x, b.y, nh2(a.w, b.x, b.y));
                dst[2] = make_float4(b.z, b.w, c.x, nh2(b.z, b.w, c.x));
                dst[3] = make_float4(c.y, c.z, c.w, nh2(c.y, c.z, c.w));
                dst[4] = make_float4(d.x, d.y, d.z, nh2(d.x, d.y, d.z));
                dst[5] = make_float4(d.w, e.x, e.y, nh2(d.w, e.x, e.y));
                dst[6] = make_float4(e.z, e.w, f.x, nh2(e.z, e.w, f.x));
                dst[7] = make_float4(f.y, f.z, f.w, nh2(f.y, f.z, f.w));
            } else {
                #pragma unroll
                for (int k = 0; k < 8; ++k) {
                    int p = p0 + k;
                    if (p < se) {
                        float sx = surf[3*p], sy = surf[3*p+1], sz = surf[3*p+2];
                        dst[k] = make_float4(sx, sy, sz, nh2(sx, sy, sz));
                    } else {
                        dst[k] = make_float4(0.f, 0.f, 0.f, -3.0e38f);
                    }
                }
            }
        }
        __syncthreads();
        // ---- scan: wave wv covers 512 pts = 8 chunks of 64 ----
        const int lo = wv * (TILE / NWAVE);
        const float4* tp = tile + lo;
        const int cidbase = (base + lo) >> 6;                 // wave-uniform
        #pragma unroll 1
        for (int c = 0; c < (TILE / NWAVE) / CHK; ++c) {
            const float4* cp = tp + c * CHK;
            #pragma unroll 8
            for (int o = 0; o < CHK; ++o) {
                float4 s4 = cp[o];                            // broadcast b128
                v2f sx = (v2f){s4.x, s4.x};
                v2f sy = (v2f){s4.y, s4.y};
                v2f sz = (v2f){s4.z, s4.z};
                v2f sw = (v2f){s4.w, s4.w};
                #pragma unroll
                for (int p = 0; p < QPL/2; ++p) {
                    v2f g = __builtin_elementwise_fma(qx2[p], sx,
                            __builtin_elementwise_fma(qy2[p], sy,
                            __builtin_elementwise_fma(qz2[p], sz, sw)));
                    float ga = g[0], gb = g[1];
                    M2[2*p]   = __builtin_amdgcn_fmed3f(ga, M1[2*p], M2[2*p]);
                    M1[2*p]   = fmaxf(M1[2*p], ga);
                    M2[2*p+1] = __builtin_amdgcn_fmed3f(gb, M1[2*p+1], M2[2*p+1]);
                    M1[2*p+1] = fmaxf(M1[2*p+1], gb);
                }
            }
            const int cid = cidbase + c;
            #pragma unroll
            for (int k = 0; k < QPL; ++k) {
                c1[k] = (M1[k] != P1[k]) ? cid : c1[k];  P1[k] = M1[k];
                c2[k] = (M2[k] != P2[k]) ? cid : c2[k];  P2[k] = M2[k];
            }
        }
    }

    // ---- merge 8 wave-partials per query, write record to ws ----
    __syncthreads();
    float4* rec = tile;                                       // reuse LDS (64 KB)
    #pragma unroll
    for (int k = 0; k < QPL; ++k)
        rec[wv * 512 + k * 64 + lane] =
            make_float4(M1[k], M2[k], __int_as_float(c1[k]), __int_as_float(c2[k]));
    __syncthreads();
    {
        float4 r = rec[t];
        float M1m = r.x, M2m = r.y;
        int C1 = __float_as_int(r.z), C2 = __float_as_int(r.w);
        #pragma unroll
        for (int w = 1; w < NWAVE; ++w) {
            float4 a = rec[w * 512 + t];
            float a1 = a.x, a2 = a.y;
            int ac1 = __float_as_int(a.z), ac2 = __float_as_int(a.w);
            if (a1 > M1m)      { M2m = M1m; C2 = C1; M1m = a1; C1 = ac1; }
            else if (a1 > M2m) { M2m = a1; C2 = ac1; }
            if (a2 > M2m)      { M2m = a2; C2 = ac2; }
        }
        int gq = qg * 512 + t;
        if (gq < QT) {
            ((float4*)(ws + WS_REC))[(size_t)gq * splits + sp] =
                make_float4(M1m, M2m, __int_as_float(C1), __int_as_float(C2));
        }
    }
}

// ---------------------------------------------------------------------------
// Index recovery, wave-per-query: 64 lanes check the tracked chunk in
// parallel (coalesced), ballot+ctz -> exact first index. Small losses fused.
// ---------------------------------------------------------------------------
__global__ __launch_bounds__(256) void recover_k(
    const float* __restrict__ offq, const float* __restrict__ nearq,
    const float* __restrict__ surf, const float* __restrict__ norms,
    const float* __restrict__ nmpred, const float* __restrict__ nppred,
    const float* __restrict__ mp, const float* __restrict__ mg,
    const float* __restrict__ sn,
    float* __restrict__ ws, int S, int Qoff, int QT, int N, int splits)
{
    const int t    = threadIdx.x;
    const int lane = t & 63;
    const int wv   = t >> 6;
    const int gw   = blockIdx.x * 4 + wv;
    const int NW   = gridDim.x * 4;

    float ori = 0.f, nori = 0.f;                 // wave-uniform accumulators
    for (int q = gw; q < QT; q += NW) {
        const float4* recs = ((const float4*)(ws + WS_REC)) + (size_t)q * splits;
        float4 r = recs[0];
        float M1 = r.x, M2 = r.y;
        int C1 = __float_as_int(r.z), C2 = __float_as_int(r.w);
        for (int i = 1; i < splits; ++i) {
            float4 a = recs[i];
            float a1 = a.x, a2 = a.y;
            int ac1 = __float_as_int(a.z), ac2 = __float_as_int(a.w);
            if (a1 > M1)      { M2 = M1; C2 = C1; M1 = a1; C1 = ac1; }
            else if (a1 > M2) { M2 = a1; C2 = ac1; }
            if (a2 > M2)      { M2 = a2; C2 = ac2; }
        }
        const bool isNear = (q >= Qoff);
        const float* qp = isNear ? (nearq + 3 * (q - Qoff)) : (offq + 3 * q);
        const float qx = qp[0], qy = qp[1], qz = qp[2];

        // chunk C1: lane checks point C1*64+lane
        int j1 = C1 * CHK + lane;
        float g1 = -3.0e38f;
        if (j1 < S) {
            float sx = surf[3*j1], sy = surf[3*j1+1], sz = surf[3*j1+2];
            g1 = score(qx, qy, qz, sx, sy, sz, nh2(sx, sy, sz));
        }
        unsigned long long mk1 = __ballot(g1 == M1);
        int I1 = mk1 ? (C1 * CHK + (int)__builtin_ctzll(mk1)) : 0;

        int j2 = C2 * CHK + lane;
        float g2 = -3.0e38f;
        if (j2 < S) {
            float sx = surf[3*j2], sy = surf[3*j2+1], sz = surf[3*j2+2];
            g2 = score(qx, qy, qz, sx, sy, sz, nh2(sx, sy, sz));
        }
        unsigned long long mk2 = __ballot(g2 == M2 && j2 != I1);
        int I2 = mk2 ? (C2 * CHK + (int)__builtin_ctzll(mk2))
                     : ((I1 == 0 && S > 1) ? 1 : 0);

        float d1 = (qx - surf[3*I1]) * norms[3*I1]
                 + (qy - surf[3*I1+1]) * norms[3*I1+1]
                 + (qz - surf[3*I1+2]) * norms[3*I1+2];
        float d2 = (qx - surf[3*I2]) * norms[3*I2]
                 + (qy - surf[3*I2+1]) * norms[3*I2+1]
                 + (qz - surf[3*I2+2]) * norms[3*I2+2];
        float ms  = d1 + d2;                                  // sign(mean)==sign(sum)
        float sgn = (ms > 0.f) ? 1.f : ((ms < 0.f) ? -1.f : 0.f);
        float pred = isNear ? nppred[q - Qoff] : nmpred[q];
        float term = fmaxf(0.f, -pred * sgn);
        if (isNear) nori += term; else ori += term;
    }

    // fused small losses (grid-stride, per-thread)
    float sdf = 0.f, eik = 0.f, gn = 0.f;
    const int gid = blockIdx.x * 256 + t;
    const int GT  = gridDim.x * 256;
    for (int i = gid; i < N; i += GT) {
        float p = mp[i];
        sdf += p * p;
        float gx = mg[3*i], gy = mg[3*i+1], gz = mg[3*i+2];
        float nrm = sqrtf(fmaf(gx, gx, fmaf(gy, gy, gz * gz)));
        float d = nrm - 1.0f;
        eik += d * d;
        float nx = sn[3*i], ny = sn[3*i+1], nz = sn[3*i+2];
        float dx = gx - nx, dy = gy - ny, dz = gz - nz;
        gn += fmaf(dx, dx, fmaf(dy, dy, dz * dz));
    }

    __shared__ float red[5][256];
    red[0][t] = (lane == 0) ? ori  : 0.f;   // wave-uniform: count once
    red[1][t] = (lane == 0) ? nori : 0.f;
    red[2][t] = sdf; red[3][t] = eik; red[4][t] = gn;
    __syncthreads();
    for (int off = 128; off > 0; off >>= 1) {
        if (t < off) {
            #pragma unroll
            for (int k = 0; k < 5; ++k) red[k][t] += red[k][t + off];
        }
        __syncthreads();
    }
    if (t == 0) {
        #pragma unroll
        for (int k = 0; k < 5; ++k) ws[k * WS_STRIDE + blockIdx.x] = red[k][0];
    }
}

// ---------------------------------------------------------------------------
__global__ __launch_bounds__(256) void final_k(
    const float* __restrict__ ws, float* __restrict__ out,
    int N, int RB, int Qoff, int Qnear)
{
    __shared__ float r[5][256];
    int t = threadIdx.x;
    float s[5] = {0.f, 0.f, 0.f, 0.f, 0.f};
    for (int i = t; i < RB; i += 256) {
        #pragma unroll
        for (int k = 0; k < 5; ++k) s[k] += ws[k * WS_STRIDE + i];
    }
    #pragma unroll
    for (int k = 0; k < 5; ++k) r[k][t] = s[k];
    __syncthreads();
    for (int off = 128; off > 0; off >>= 1) {
        if (t < off) {
            #pragma unroll
            for (int k = 0; k < 5; ++k) r[k][t] += r[k][t + off];
        }
        __syncthreads();
    }
    if (t == 0) {
        float orim  = r[0][0] / (float)Qoff;
        float norim = r[1][0] / (float)Qnear;
        float sdfm  = r[2][0] / (float)N;
        float eikm  = r[3][0] / (float)N;
        float gnm   = r[4][0] / (3.0f * (float)N);
        out[0] = SDF_W * sdfm + EIK_W * eikm + ORI_W * orim
               + NEAR_ORI_W * norim + GRADN_W * gnm;
        out[1] = sdfm;
        out[2] = eikm;
        out[3] = orim;
        out[4] = norim;
        out[5] = gnm;
    }
}

extern "C" void kernel_launch(void* const* d_in, const int* in_sizes, int n_in,
                              void* d_out, int out_size, void* d_ws, size_t ws_size,
                              hipStream_t stream)
{
    const float* mp    = (const float*)d_in[0];  // manifold_pred      [N,1]
    const float* mg    = (const float*)d_in[1];  // manifold_grad      [N,3]
    const float* nmp   = (const float*)d_in[2];  // nonmanifold_pred   [N,1]
    const float* npp   = (const float*)d_in[3];  // near_points_pred   [N,1]
    const float* sp    = (const float*)d_in[4];  // surface_points     [S,3]
    const float* sn    = (const float*)d_in[5];  // surface_normals    [S,3]
    const float* offp  = (const float*)d_in[6];  // off_surface_points [Q,3]
    const float* nearp = (const float*)d_in[7];  // near_points        [Q,3]
    float* out = (float*)d_out;

    const int N     = in_sizes[0];
    const int S     = in_sizes[4] / 3;
    const int Qoff  = in_sizes[2];
    const int Qnear = in_sizes[3];
    const int QT    = Qoff + Qnear;

    float* ws = (float*)d_ws;

    const int qgroups = (QT + 511) / 512;
    // splits=4 needs 16KB + QT*4*16B of ws; fall back to 2 (proven footprint).
    size_t need4 = (size_t)WS_REC * 4 + (size_t)QT * 4 * 16 + 1024;
    const int splits = (ws_size >= need4) ? 4 : 2;
    const int segLen = ((S + splits - 1) / splits + CHK - 1) / CHK * CHK;

    const int RB = 256;
    nn_scan<<<qgroups * splits, 512, 0, stream>>>(offp, nearp, sp, ws,
                                                  S, Qoff, QT, splits, segLen);
    recover_k<<<RB, 256, 0, stream>>>(offp, nearp, sp, sn, nmp, npp,
                                      mp, mg, sn, ws, S, Qoff, QT, N, splits);
    final_k<<<1, 256, 0, stream>>>(ws, out, N, RB, Qoff, Qnear);
}

// Round 5
// 184.806 us; speedup vs baseline: 1.0660x; 1.0660x over previous
//
#include <hip/hip_runtime.h>
#include <math.h>

#define SDF_W      7000.0f
#define EIK_W      600.0f
#define ORI_W      500.0f
#define NEAR_ORI_W 10.0f
#define GRADN_W    200.0f

#define TILE   2048          // points per LDS tile (32 KB of float4)
#define NWAVE  8             // 512-thread blocks
#define QPL    8             // queries per lane -> 512 queries per block
#define CHK    64            // chunk granularity for index recovery (= wave size)
#define WS_STRIDE 512        // per-array stride (floats) for block partials
#define WS_REC 4096          // float offset of per-query records

typedef float v2f __attribute__((ext_vector_type(2)));

// ws float layout:
//   [k*512 .. k*512+RB) : recover-block partials, k = 0:ori 1:nori 2:sdf 3:eik 4:gn
//   [4096 ...)          : records, float4 per (query, split): {M1, M2, c1, c2}

__device__ __forceinline__ float nh2(float sx, float sy, float sz) {
    return -0.5f * fmaf(sx, sx, fmaf(sy, sy, sz * sz));
}
// Deterministic score; bit-identical chain in nn_scan and recover_k.
__device__ __forceinline__ float score(float qx, float qy, float qz,
                                       float sx, float sy, float sz, float nh) {
    return fmaf(qx, sx, fmaf(qy, sy, fmaf(qz, sz, nh)));
}

// ---------------------------------------------------------------------------
// Hot kernel: top-2 score values per (query, S-split) + chunk ids.
// 8 queries/lane (512/block); 8 waves split the 2048-pt tile; `splits` blocks
// split S -> grid = qgroups*splits (512 at default shape = 2 blocks/CU,
// 4 waves/SIMD for latency hiding; this was 1 block/CU in R4 = the regression).
// Inner update: M2 = med3(g, M1, M2); M1 = max(M1, g)  (2 ops, no indices).
// ---------------------------------------------------------------------------
__global__ __launch_bounds__(512, 4) void nn_scan(
    const float* __restrict__ offq, const float* __restrict__ nearq,
    const float* __restrict__ surf,
    float* __restrict__ ws, int S, int Qoff, int QT, int splits, int segLen)
{
    __shared__ float4 tile[TILE];                 // 32 KB; reused for merge recs
    const int t    = threadIdx.x;
    const int lane = t & 63;
    const int wv   = __builtin_amdgcn_readfirstlane(t >> 6);   // 0..7

    const int qg = blockIdx.x / splits;
    const int sp = blockIdx.x % splits;
    const int sb = sp * segLen;
    int se = sb + segLen; if (se > S) se = S;

    // ---- load 8 queries per lane ----
    float qx[QPL], qy[QPL], qz[QPL];
    #pragma unroll
    for (int k = 0; k < QPL; ++k) {
        int q = qg * 512 + k * 64 + lane;
        float x = 0.f, y = 0.f, z = 0.f;
        if (q < QT) {
            const float* p = (q < Qoff) ? (offq + 3 * q) : (nearq + 3 * (q - Qoff));
            x = p[0]; y = p[1]; z = p[2];
        }
        qx[k] = x; qy[k] = y; qz[k] = z;
    }
    v2f qx2[QPL/2], qy2[QPL/2], qz2[QPL/2];
    #pragma unroll
    for (int p = 0; p < QPL/2; ++p) {
        qx2[p] = (v2f){qx[2*p], qx[2*p+1]};
        qy2[p] = (v2f){qy[2*p], qy[2*p+1]};
        qz2[p] = (v2f){qz[2*p], qz[2*p+1]};
    }

    float M1[QPL], M2[QPL], P1[QPL], P2[QPL];
    int   c1[QPL], c2[QPL];
    const int cinit = (sb < S ? sb : 0) >> 6;
    #pragma unroll
    for (int k = 0; k < QPL; ++k) {
        M1[k] = -3.0e38f; M2[k] = -3.0e38f;
        P1[k] = -3.0e38f; P2[k] = -3.0e38f;
        c1[k] = cinit;    c2[k] = cinit;
    }

    for (int base = sb; base < se; base += TILE) {
        __syncthreads();
        // ---- stage TILE points, lane-contiguous: coalesced global reads,
        //      conflict-free ds_write (16B lane stride) ----
        #pragma unroll
        for (int k = 0; k < TILE / 512; ++k) {
            int li = k * 512 + t;
            int p  = base + li;
            float sx = 0.f, sy = 0.f, sz = 0.f, w = -3.0e38f;
            if (p < se) {
                sx = surf[3*p]; sy = surf[3*p+1]; sz = surf[3*p+2];
                w  = nh2(sx, sy, sz);
            }
            tile[li] = make_float4(sx, sy, sz, w);
        }
        __syncthreads();
        // ---- scan: wave wv covers 256 pts = 4 chunks of 64 ----
        const int lo = wv * (TILE / NWAVE);
        const float4* tp = tile + lo;
        const int cidbase = (base + lo) >> 6;                 // wave-uniform
        #pragma unroll 1
        for (int c = 0; c < (TILE / NWAVE) / CHK; ++c) {
            const float4* cp = tp + c * CHK;
            #pragma unroll 8
            for (int o = 0; o < CHK; ++o) {
                float4 s4 = cp[o];                            // broadcast b128
                v2f sx = (v2f){s4.x, s4.x};
                v2f sy = (v2f){s4.y, s4.y};
                v2f sz = (v2f){s4.z, s4.z};
                v2f sw = (v2f){s4.w, s4.w};
                #pragma unroll
                for (int p = 0; p < QPL/2; ++p) {
                    v2f g = __builtin_elementwise_fma(qx2[p], sx,
                            __builtin_elementwise_fma(qy2[p], sy,
                            __builtin_elementwise_fma(qz2[p], sz, sw)));
                    float ga = g[0], gb = g[1];
                    M2[2*p]   = __builtin_amdgcn_fmed3f(ga, M1[2*p], M2[2*p]);
                    M1[2*p]   = fmaxf(M1[2*p], ga);
                    M2[2*p+1] = __builtin_amdgcn_fmed3f(gb, M1[2*p+1], M2[2*p+1]);
                    M1[2*p+1] = fmaxf(M1[2*p+1], gb);
                }
            }
            const int cid = cidbase + c;
            #pragma unroll
            for (int k = 0; k < QPL; ++k) {
                c1[k] = (M1[k] != P1[k]) ? cid : c1[k];  P1[k] = M1[k];
                c2[k] = (M2[k] != P2[k]) ? cid : c2[k];  P2[k] = M2[k];
            }
        }
    }

    // ---- hierarchical 8-wave merge in 32 KB LDS (tile reused) ----
    float4* rec = tile;
    __syncthreads();
    // step 1: waves 4..7 publish
    if (wv >= 4) {
        #pragma unroll
        for (int k = 0; k < QPL; ++k)
            rec[(wv - 4) * 512 + k * 64 + lane] =
                make_float4(M1[k], M2[k], __int_as_float(c1[k]), __int_as_float(c2[k]));
    }
    __syncthreads();
    if (wv < 4) {
        #pragma unroll
        for (int k = 0; k < QPL; ++k) {
            float4 a = rec[wv * 512 + k * 64 + lane];
            float a1 = a.x, a2 = a.y;
            int ac1 = __float_as_int(a.z), ac2 = __float_as_int(a.w);
            if (a1 > M1[k])      { M2[k] = M1[k]; c2[k] = c1[k]; M1[k] = a1; c1[k] = ac1; }
            else if (a1 > M2[k]) { M2[k] = a1; c2[k] = ac1; }
            if (a2 > M2[k])      { M2[k] = a2; c2[k] = ac2; }
        }
    }
    __syncthreads();
    // step 2: waves 2,3 publish
    if (wv == 2 || wv == 3) {
        #pragma unroll
        for (int k = 0; k < QPL; ++k)
            rec[(wv - 2) * 512 + k * 64 + lane] =
                make_float4(M1[k], M2[k], __int_as_float(c1[k]), __int_as_float(c2[k]));
    }
    __syncthreads();
    if (wv < 2) {
        #pragma unroll
        for (int k = 0; k < QPL; ++k) {
            float4 a = rec[wv * 512 + k * 64 + lane];
            float a1 = a.x, a2 = a.y;
            int ac1 = __float_as_int(a.z), ac2 = __float_as_int(a.w);
            if (a1 > M1[k])      { M2[k] = M1[k]; c2[k] = c1[k]; M1[k] = a1; c1[k] = ac1; }
            else if (a1 > M2[k]) { M2[k] = a1; c2[k] = ac1; }
            if (a2 > M2[k])      { M2[k] = a2; c2[k] = ac2; }
        }
    }
    __syncthreads();
    // step 3: wave 1 publishes, wave 0 finishes + writes records
    if (wv == 1) {
        #pragma unroll
        for (int k = 0; k < QPL; ++k)
            rec[k * 64 + lane] =
                make_float4(M1[k], M2[k], __int_as_float(c1[k]), __int_as_float(c2[k]));
    }
    __syncthreads();
    if (wv == 0) {
        #pragma unroll
        for (int k = 0; k < QPL; ++k) {
            float4 a = rec[k * 64 + lane];
            float a1 = a.x, a2 = a.y;
            int ac1 = __float_as_int(a.z), ac2 = __float_as_int(a.w);
            if (a1 > M1[k])      { M2[k] = M1[k]; c2[k] = c1[k]; M1[k] = a1; c1[k] = ac1; }
            else if (a1 > M2[k]) { M2[k] = a1; c2[k] = ac1; }
            if (a2 > M2[k])      { M2[k] = a2; c2[k] = ac2; }
            int gq = qg * 512 + k * 64 + lane;
            if (gq < QT)
                ((float4*)(ws + WS_REC))[(size_t)gq * splits + sp] =
                    make_float4(M1[k], M2[k], __int_as_float(c1[k]), __int_as_float(c2[k]));
        }
    }
}

// ---------------------------------------------------------------------------
// Index recovery, wave-per-query: 64 lanes check the tracked chunk in
// parallel (coalesced), ballot+ctz -> exact first index. Small losses fused.
// ---------------------------------------------------------------------------
__global__ __launch_bounds__(256) void recover_k(
    const float* __restrict__ offq, const float* __restrict__ nearq,
    const float* __restrict__ surf, const float* __restrict__ norms,
    const float* __restrict__ nmpred, const float* __restrict__ nppred,
    const float* __restrict__ mp, const float* __restrict__ mg,
    const float* __restrict__ sn,
    float* __restrict__ ws, int S, int Qoff, int QT, int N, int splits)
{
    const int t    = threadIdx.x;
    const int lane = t & 63;
    const int wv   = t >> 6;
    const int gw   = blockIdx.x * 4 + wv;
    const int NW   = gridDim.x * 4;

    float ori = 0.f, nori = 0.f;                 // wave-uniform accumulators
    for (int q = gw; q < QT; q += NW) {
        const float4* recs = ((const float4*)(ws + WS_REC)) + (size_t)q * splits;
        float4 r = recs[0];
        float M1 = r.x, M2 = r.y;
        int C1 = __float_as_int(r.z), C2 = __float_as_int(r.w);
        for (int i = 1; i < splits; ++i) {
            float4 a = recs[i];
            float a1 = a.x, a2 = a.y;
            int ac1 = __float_as_int(a.z), ac2 = __float_as_int(a.w);
            if (a1 > M1)      { M2 = M1; C2 = C1; M1 = a1; C1 = ac1; }
            else if (a1 > M2) { M2 = a1; C2 = ac1; }
            if (a2 > M2)      { M2 = a2; C2 = ac2; }
        }
        const bool isNear = (q >= Qoff);
        const float* qp = isNear ? (nearq + 3 * (q - Qoff)) : (offq + 3 * q);
        const float qx = qp[0], qy = qp[1], qz = qp[2];

        int j1 = C1 * CHK + lane;
        float g1 = -3.0e38f;
        if (j1 < S) {
            float sx = surf[3*j1], sy = surf[3*j1+1], sz = surf[3*j1+2];
            g1 = score(qx, qy, qz, sx, sy, sz, nh2(sx, sy, sz));
        }
        unsigned long long mk1 = __ballot(g1 == M1);
        int I1 = mk1 ? (C1 * CHK + (int)__builtin_ctzll(mk1)) : 0;

        int j2 = C2 * CHK + lane;
        float g2 = -3.0e38f;
        if (j2 < S) {
            float sx = surf[3*j2], sy = surf[3*j2+1], sz = surf[3*j2+2];
            g2 = score(qx, qy, qz, sx, sy, sz, nh2(sx, sy, sz));
        }
        unsigned long long mk2 = __ballot(g2 == M2 && j2 != I1);
        int I2 = mk2 ? (C2 * CHK + (int)__builtin_ctzll(mk2))
                     : ((I1 == 0 && S > 1) ? 1 : 0);

        float d1 = (qx - surf[3*I1]) * norms[3*I1]
                 + (qy - surf[3*I1+1]) * norms[3*I1+1]
                 + (qz - surf[3*I1+2]) * norms[3*I1+2];
        float d2 = (qx - surf[3*I2]) * norms[3*I2]
                 + (qy - surf[3*I2+1]) * norms[3*I2+1]
                 + (qz - surf[3*I2+2]) * norms[3*I2+2];
        float ms  = d1 + d2;                                  // sign(mean)==sign(sum)
        float sgn = (ms > 0.f) ? 1.f : ((ms < 0.f) ? -1.f : 0.f);
        float pred = isNear ? nppred[q - Qoff] : nmpred[q];
        float term = fmaxf(0.f, -pred * sgn);
        if (isNear) nori += term; else ori += term;
    }

    // fused small losses (grid-stride, per-thread)
    float sdf = 0.f, eik = 0.f, gn = 0.f;
    const int gid = blockIdx.x * 256 + t;
    const int GT  = gridDim.x * 256;
    for (int i = gid; i < N; i += GT) {
        float p = mp[i];
        sdf += p * p;
        float gx = mg[3*i], gy = mg[3*i+1], gz = mg[3*i+2];
        float nrm = sqrtf(fmaf(gx, gx, fmaf(gy, gy, gz * gz)));
        float d = nrm - 1.0f;
        eik += d * d;
        float nx = sn[3*i], ny = sn[3*i+1], nz = sn[3*i+2];
        float dx = gx - nx, dy = gy - ny, dz = gz - nz;
        gn += fmaf(dx, dx, fmaf(dy, dy, dz * dz));
    }

    __shared__ float red[5][256];
    red[0][t] = (lane == 0) ? ori  : 0.f;   // wave-uniform: count once
    red[1][t] = (lane == 0) ? nori : 0.f;
    red[2][t] = sdf; red[3][t] = eik; red[4][t] = gn;
    __syncthreads();
    for (int off = 128; off > 0; off >>= 1) {
        if (t < off) {
            #pragma unroll
            for (int k = 0; k < 5; ++k) red[k][t] += red[k][t + off];
        }
        __syncthreads();
    }
    if (t == 0) {
        #pragma unroll
        for (int k = 0; k < 5; ++k) ws[k * WS_STRIDE + blockIdx.x] = red[k][0];
    }
}

// ---------------------------------------------------------------------------
__global__ __launch_bounds__(256) void final_k(
    const float* __restrict__ ws, float* __restrict__ out,
    int N, int RB, int Qoff, int Qnear)
{
    __shared__ float r[5][256];
    int t = threadIdx.x;
    float s[5] = {0.f, 0.f, 0.f, 0.f, 0.f};
    for (int i = t; i < RB; i += 256) {
        #pragma unroll
        for (int k = 0; k < 5; ++k) s[k] += ws[k * WS_STRIDE + i];
    }
    #pragma unroll
    for (int k = 0; k < 5; ++k) r[k][t] = s[k];
    __syncthreads();
    for (int off = 128; off > 0; off >>= 1) {
        if (t < off) {
            #pragma unroll
            for (int k = 0; k < 5; ++k) r[k][t] += r[k][t + off];
        }
        __syncthreads();
    }
    if (t == 0) {
        float orim  = r[0][0] / (float)Qoff;
        float norim = r[1][0] / (float)Qnear;
        float sdfm  = r[2][0] / (float)N;
        float eikm  = r[3][0] / (float)N;
        float gnm   = r[4][0] / (3.0f * (float)N);
        out[0] = SDF_W * sdfm + EIK_W * eikm + ORI_W * orim
               + NEAR_ORI_W * norim + GRADN_W * gnm;
        out[1] = sdfm;
        out[2] = eikm;
        out[3] = orim;
        out[4] = norim;
        out[5] = gnm;
    }
}

extern "C" void kernel_launch(void* const* d_in, const int* in_sizes, int n_in,
                              void* d_out, int out_size, void* d_ws, size_t ws_size,
                              hipStream_t stream)
{
    const float* mp    = (const float*)d_in[0];  // manifold_pred      [N,1]
    const float* mg    = (const float*)d_in[1];  // manifold_grad      [N,3]
    const float* nmp   = (const float*)d_in[2];  // nonmanifold_pred   [N,1]
    const float* npp   = (const float*)d_in[3];  // near_points_pred   [N,1]
    const float* sp    = (const float*)d_in[4];  // surface_points     [S,3]
    const float* sn    = (const float*)d_in[5];  // surface_normals    [S,3]
    const float* offp  = (const float*)d_in[6];  // off_surface_points [Q,3]
    const float* nearp = (const float*)d_in[7];  // near_points        [Q,3]
    float* out = (float*)d_out;

    const int N     = in_sizes[0];
    const int S     = in_sizes[4] / 3;
    const int Qoff  = in_sizes[2];
    const int Qnear = in_sizes[3];
    const int QT    = Qoff + Qnear;

    float* ws = (float*)d_ws;

    const int qgroups = (QT + 511) / 512;
    // splits=8 -> grid 512 blocks (2/CU). Fall back if ws too small.
    size_t need8 = (size_t)WS_REC * 4 + (size_t)QT * 8 * 16 + 1024;
    size_t need4 = (size_t)WS_REC * 4 + (size_t)QT * 4 * 16 + 1024;
    const int splits = (ws_size >= need8) ? 8 : ((ws_size >= need4) ? 4 : 2);
    const int segLen = (((S + splits - 1) / splits) + CHK - 1) / CHK * CHK;

    const int RB = 512;
    nn_scan<<<qgroups * splits, 512, 0, stream>>>(offp, nearp, sp, ws,
                                                  S, Qoff, QT, splits, segLen);
    recover_k<<<RB, 256, 0, stream>>>(offp, nearp, sp, sn, nmp, npp,
                                      mp, mg, sn, ws, S, Qoff, QT, N, splits);
    final_k<<<1, 256, 0, stream>>>(ws, out, N, RB, Qoff, Qnear);
}